// Round 1
// baseline (526.516 us; speedup 1.0000x reference)
//
#include <hip/hip_runtime.h>

#define DIM 512
#define HEADS 8
#define HD 64
#define BATCH 4
#define NQ 2048
#define MA 2048
#define MS 256
#define TM 32
#define KSTR 72   // K LDS row stride (elems): 144B rows -> 16B-aligned b128, 2-way banks
#define VSTR 66   // V LDS row stride: odd-ish stride spreads banks for scalar gathers
#define PSTR 40   // P LDS row stride: 80B rows -> 16B-aligned b128 reads

typedef __attribute__((ext_vector_type(8))) short bf16x8;
typedef __attribute__((ext_vector_type(4))) float f32x4;

__device__ __forceinline__ ushort f2b(float f) {
    // RNE float -> bf16 bits (inputs finite; no NaN handling needed)
    uint u = __float_as_uint(f);
    u = (u + 0x7fffu + ((u >> 16) & 1u)) >> 16;
    return (ushort)u;
}

__global__ __launch_bounds__(256) void cast_w(const float* __restrict__ in,
                                              ushort* __restrict__ out, int n4) {
    int i = blockIdx.x * 256 + threadIdx.x;
    if (i < n4) {
        float4 v = ((const float4*)in)[i];
        ushort4 o;
        o.x = f2b(v.x); o.y = f2b(v.y); o.z = f2b(v.z); o.w = f2b(v.w);
        ((ushort4*)out)[i] = o;
    }
}

// Y[M x 512] = A[M x 512](fp32) @ W^T (W bf16 [512][512] row-major = B^T layout) + bias; out bf16
__global__ __launch_bounds__(256) void gemm_a32(const float* __restrict__ A,
                                                const ushort* __restrict__ W,
                                                const float* __restrict__ bias,
                                                ushort* __restrict__ out, int M) {
    int tid = threadIdx.x;
    int wv = tid >> 6, ln = tid & 63, l = ln & 15, g = ln >> 4;
    int row0 = blockIdx.x * 64 + wv * 16;
    int col0 = blockIdx.y * 64;
    const float* ap = A + (size_t)(row0 + l) * DIM + g * 8;
    const ushort* wp = W + (size_t)(col0 + l) * DIM + g * 8;
    f32x4 acc[4] = {{0,0,0,0},{0,0,0,0},{0,0,0,0},{0,0,0,0}};
    for (int kk = 0; kk < DIM; kk += 32) {
        float4 f0 = *(const float4*)(ap + kk);
        float4 f1 = *(const float4*)(ap + kk + 4);
        bf16x8 a;
        a[0] = (short)f2b(f0.x); a[1] = (short)f2b(f0.y);
        a[2] = (short)f2b(f0.z); a[3] = (short)f2b(f0.w);
        a[4] = (short)f2b(f1.x); a[5] = (short)f2b(f1.y);
        a[6] = (short)f2b(f1.z); a[7] = (short)f2b(f1.w);
#pragma unroll
        for (int c = 0; c < 4; c++) {
            bf16x8 b = *(const bf16x8*)(wp + (size_t)c * 16 * DIM + kk);
            acc[c] = __builtin_amdgcn_mfma_f32_16x16x32_bf16(a, b, acc[c], 0, 0, 0);
        }
    }
#pragma unroll
    for (int c = 0; c < 4; c++) {
        int col = col0 + c * 16 + l;
        float bv = bias[col];
#pragma unroll
        for (int r = 0; r < 4; r++) {
            int row = row0 + g * 4 + r;
            out[(size_t)row * DIM + col] = f2b(acc[c][r] + bv);
        }
    }
}

// Y[M x 512](fp32) = A[M x 512](bf16) @ W^T + bias  (final projection)
__global__ __launch_bounds__(256) void gemm_a16(const ushort* __restrict__ A,
                                                const ushort* __restrict__ W,
                                                const float* __restrict__ bias,
                                                float* __restrict__ out, int M) {
    int tid = threadIdx.x;
    int wv = tid >> 6, ln = tid & 63, l = ln & 15, g = ln >> 4;
    int row0 = blockIdx.x * 64 + wv * 16;
    int col0 = blockIdx.y * 64;
    const ushort* ap = A + (size_t)(row0 + l) * DIM + g * 8;
    const ushort* wp = W + (size_t)(col0 + l) * DIM + g * 8;
    f32x4 acc[4] = {{0,0,0,0},{0,0,0,0},{0,0,0,0},{0,0,0,0}};
    for (int kk = 0; kk < DIM; kk += 32) {
        bf16x8 a = *(const bf16x8*)(ap + kk);
#pragma unroll
        for (int c = 0; c < 4; c++) {
            bf16x8 b = *(const bf16x8*)(wp + (size_t)c * 16 * DIM + kk);
            acc[c] = __builtin_amdgcn_mfma_f32_16x16x32_bf16(a, b, acc[c], 0, 0, 0);
        }
    }
#pragma unroll
    for (int c = 0; c < 4; c++) {
        int col = col0 + c * 16 + l;
        float bv = bias[col];
#pragma unroll
        for (int r = 0; r < 4; r++) {
            int row = row0 + g * 4 + r;
            out[(size_t)row * DIM + col] = acc[c][r] + bv;
        }
    }
}

// One context's flash loop. Each wave owns 16 query rows; block of 4 waves shares K/V tiles.
__device__ __forceinline__ void attn_ctx(const ushort* __restrict__ K,
                                         const ushort* __restrict__ V,
                                         int M, int bi, int h,
                                         bf16x8 a0, bf16x8 a1,
                                         ushort* Klds, ushort* Vlds, ushort* Pw,
                                         f32x4 (&acc)[4], float (&mi)[4], float (&li)[4],
                                         int tid) {
    const float scale = 0.044194173824159216f;  // 512^-0.5
    int ln = tid & 63, l = ln & 15, g = ln >> 4;
    int sr = tid >> 3;            // staging row 0..31
    int scb = (tid & 7) * 8;      // staging col base
    for (int mt = 0; mt < M; mt += TM) {
        __syncthreads();
        // stage K tile (32x64) -> Klds stride 72, 16B aligned stores
        const ushort* kg = K + (size_t)(bi * M + mt + sr) * DIM + h * HD + scb;
        bf16x8 kv = *(const bf16x8*)kg;
        *(bf16x8*)(Klds + sr * KSTR + scb) = kv;
        // stage V tile -> Vlds stride 66 (4B-aligned dword stores)
        const ushort* vg = V + (size_t)(bi * M + mt + sr) * DIM + h * HD + scb;
        bf16x8 vv = *(const bf16x8*)vg;
        union { bf16x8 v; uint u[4]; } cvt; cvt.v = vv;
        uint* vd = (uint*)(Vlds + sr * VSTR + scb);
        vd[0] = cvt.u[0]; vd[1] = cvt.u[1]; vd[2] = cvt.u[2]; vd[3] = cvt.u[3];
        __syncthreads();

        // S = Q K^T for 16 queries x 32 context cols (2 col-tiles, 2 k-chunks each)
        f32x4 s0 = {0,0,0,0}, s1 = {0,0,0,0};
        bf16x8 kb;
        kb = *(const bf16x8*)(Klds + l * KSTR + g * 8);             s0 = __builtin_amdgcn_mfma_f32_16x16x32_bf16(a0, kb, s0, 0,0,0);
        kb = *(const bf16x8*)(Klds + l * KSTR + 32 + g * 8);        s0 = __builtin_amdgcn_mfma_f32_16x16x32_bf16(a1, kb, s0, 0,0,0);
        kb = *(const bf16x8*)(Klds + (16 + l) * KSTR + g * 8);      s1 = __builtin_amdgcn_mfma_f32_16x16x32_bf16(a0, kb, s1, 0,0,0);
        kb = *(const bf16x8*)(Klds + (16 + l) * KSTR + 32 + g * 8); s1 = __builtin_amdgcn_mfma_f32_16x16x32_bf16(a1, kb, s1, 0,0,0);

        // online softmax: lane holds rows g*4+r, cols l (s0) and 16+l (s1)
#pragma unroll
        for (int r = 0; r < 4; r++) {
            float v0 = s0[r] * scale, v1 = s1[r] * scale;
            float cm = fmaxf(v0, v1);
#pragma unroll
            for (int off = 1; off < 16; off <<= 1) cm = fmaxf(cm, __shfl_xor(cm, off));
            float mn = fmaxf(mi[r], cm);
            float al = __expf(mi[r] - mn);
            float p0 = __expf(v0 - mn), p1 = __expf(v1 - mn);
            float ps = p0 + p1;
#pragma unroll
            for (int off = 1; off < 16; off <<= 1) ps += __shfl_xor(ps, off);
            li[r] = li[r] * al + ps;
            mi[r] = mn;
#pragma unroll
            for (int c = 0; c < 4; c++) acc[c][r] *= al;
            // P (C-layout) -> LDS for A-layout reload
            Pw[(g * 4 + r) * PSTR + l] = f2b(p0);
            Pw[(g * 4 + r) * PSTR + 16 + l] = f2b(p1);
        }
        // PV: O[16q x 64d] += P[16 x 32] @ V[32 x 64]
        bf16x8 pa = *(const bf16x8*)(Pw + l * PSTR + g * 8);
#pragma unroll
        for (int c = 0; c < 4; c++) {
            bf16x8 vb;
#pragma unroll
            for (int j = 0; j < 8; j++)
                vb[j] = (short)Vlds[(g * 8 + j) * VSTR + c * 16 + l];
            acc[c] = __builtin_amdgcn_mfma_f32_16x16x32_bf16(pa, vb, acc[c], 0, 0, 0);
        }
    }
}

__global__ __launch_bounds__(256) void attn_kernel(const ushort* __restrict__ q,
                                                   const ushort* __restrict__ ka,
                                                   const ushort* __restrict__ va,
                                                   const ushort* __restrict__ ks,
                                                   const ushort* __restrict__ vs,
                                                   ushort* __restrict__ y) {
    __shared__ ushort Klds[TM * KSTR];
    __shared__ ushort Vlds[TM * VSTR];
    __shared__ ushort Plds[4 * 16 * PSTR];
    int tid = threadIdx.x;
    int wv = tid >> 6, ln = tid & 63, l = ln & 15, g = ln >> 4;
    int h = blockIdx.y, bi = blockIdx.z;
    int q0 = blockIdx.x * 64 + wv * 16;
    const ushort* qp = q + (size_t)(bi * NQ + q0 + l) * DIM + h * HD + g * 8;
    bf16x8 a0 = *(const bf16x8*)qp;
    bf16x8 a1 = *(const bf16x8*)(qp + 32);
    ushort* Pw = Plds + wv * 16 * PSTR;

    f32x4 acc[4] = {{0,0,0,0},{0,0,0,0},{0,0,0,0},{0,0,0,0}};
    float mi[4] = {-1e30f, -1e30f, -1e30f, -1e30f};
    float li[4] = {0.f, 0.f, 0.f, 0.f};
    attn_ctx(ka, va, MA, bi, h, a0, a1, Klds, Vlds, Pw, acc, mi, li, tid);

    float yv[4][4];
#pragma unroll
    for (int c = 0; c < 4; c++)
#pragma unroll
        for (int r = 0; r < 4; r++) yv[c][r] = acc[c][r] / li[r];

#pragma unroll
    for (int c = 0; c < 4; c++) acc[c] = (f32x4){0,0,0,0};
#pragma unroll
    for (int r = 0; r < 4; r++) { mi[r] = -1e30f; li[r] = 0.f; }
    attn_ctx(ks, vs, MS, bi, h, a0, a1, Klds, Vlds, Pw, acc, mi, li, tid);

#pragma unroll
    for (int c = 0; c < 4; c++)
#pragma unroll
        for (int r = 0; r < 4; r++) {
            float v = yv[c][r] + acc[c][r] / li[r];
            y[(size_t)(bi * NQ + q0 + g * 4 + r) * DIM + h * HD + c * 16 + l] = f2b(v);
        }
}

extern "C" void kernel_launch(void* const* d_in, const int* in_sizes, int n_in,
                              void* d_out, int out_size, void* d_ws, size_t ws_size,
                              hipStream_t stream) {
    const float* x   = (const float*)d_in[0];
    const float* ac  = (const float*)d_in[1];
    const float* scx = (const float*)d_in[2];
    const float* Wq  = (const float*)d_in[3];
    const float* bq  = (const float*)d_in[4];
    const float* Wka = (const float*)d_in[5];
    const float* bka = (const float*)d_in[6];
    const float* Wva = (const float*)d_in[7];
    const float* bva = (const float*)d_in[8];
    const float* Wks = (const float*)d_in[9];
    const float* bks = (const float*)d_in[10];
    const float* Wvs = (const float*)d_in[11];
    const float* bvs = (const float*)d_in[12];
    const float* Wp  = (const float*)d_in[13];
    const float* bp  = (const float*)d_in[14];

    ushort* wqb  = (ushort*)d_ws;               // 6 x 262144 weight elems
    ushort* wkab = wqb  + 262144;
    ushort* wvab = wkab + 262144;
    ushort* wksb = wvab + 262144;
    ushort* wvsb = wksb + 262144;
    ushort* wpb  = wvsb + 262144;
    ushort* qb   = wpb  + 262144;               // 4194304
    ushort* kab  = qb   + 4194304;
    ushort* vab  = kab  + 4194304;
    ushort* ksb  = vab  + 4194304;              // 524288
    ushort* vsb  = ksb  + 524288;
    ushort* yb   = vsb  + 524288;               // 4194304
    // total ~37 MB of workspace

    cast_w<<<256, 256, 0, stream>>>(Wq,  wqb,  65536);
    cast_w<<<256, 256, 0, stream>>>(Wka, wkab, 65536);
    cast_w<<<256, 256, 0, stream>>>(Wva, wvab, 65536);
    cast_w<<<256, 256, 0, stream>>>(Wks, wksb, 65536);
    cast_w<<<256, 256, 0, stream>>>(Wvs, wvsb, 65536);
    cast_w<<<256, 256, 0, stream>>>(Wp,  wpb,  65536);

    gemm_a32<<<dim3(128, 8), 256, 0, stream>>>(x,   wqb,  bq,  qb,  8192);
    gemm_a32<<<dim3(128, 8), 256, 0, stream>>>(ac,  wkab, bka, kab, 8192);
    gemm_a32<<<dim3(128, 8), 256, 0, stream>>>(ac,  wvab, bva, vab, 8192);
    gemm_a32<<<dim3(16, 8),  256, 0, stream>>>(scx, wksb, bks, ksb, 1024);
    gemm_a32<<<dim3(16, 8),  256, 0, stream>>>(scx, wvsb, bvs, vsb, 1024);

    attn_kernel<<<dim3(32, 8, 4), 256, 0, stream>>>(qb, kab, vab, ksb, vsb, yb);

    gemm_a16<<<dim3(128, 8), 256, 0, stream>>>(yb, wpb, bp, (float*)d_out, 8192);
}

// Round 2
// 299.360 us; speedup vs baseline: 1.7588x; 1.7588x over previous
//
#include <hip/hip_runtime.h>

// R1: attention rebuilt (TM=64, 32q/wave, V^T produced by GEMM operand swap,
// max-free online softmax); all 6 GEMMs use m97-style 128x128 tile with
// global_load_lds(16B) for bf16 operands + in-reg f32->bf16 convert staging.
#define DIM 512
#define NQ 2048
#define MA 2048
#define MS 256
#define SCALE 0.04419417382415922f  // 512^-0.5

typedef __attribute__((ext_vector_type(8))) short bf16x8;
typedef __attribute__((ext_vector_type(4))) float f32x4;

__device__ __forceinline__ ushort f2b(float f) {
    uint u = __float_as_uint(f);
    u = (u + 0x7fffu + ((u >> 16) & 1u)) >> 16;
    return (ushort)u;
}

__device__ __forceinline__ void gload16(const ushort* g, ushort* l) {
    __builtin_amdgcn_global_load_lds(
        (const __attribute__((address_space(1))) void*)g,
        (__attribute__((address_space(3))) void*)l, 16, 0, 0);
}

__global__ __launch_bounds__(256) void cast_w6(const float* __restrict__ w0,
                                               const float* __restrict__ w1,
                                               const float* __restrict__ w2,
                                               const float* __restrict__ w3,
                                               const float* __restrict__ w4,
                                               const float* __restrict__ w5,
                                               ushort* __restrict__ out) {
    const float* ws[6] = {w0, w1, w2, w3, w4, w5};
    const float* src = ws[blockIdx.y];
    ushort* dst = out + (size_t)blockIdx.y * 262144;
    int i = blockIdx.x * 256 + threadIdx.x;  // 65536 float4 per weight
    float4 v = ((const float4*)src)[i];
    ushort4 o;
    o.x = f2b(v.x); o.y = f2b(v.y); o.z = f2b(v.z); o.w = f2b(v.w);
    ((ushort4*)dst)[i] = o;
}

// C[M x N] = A[M x K] @ B[N x K]^T + bias.  128x128 tile, BK=32, 4 waves 2x2.
// CVTA/CVTB: operand is fp32, stage with in-register convert; else bf16 via
// global_load_lds width=16.  BIAS_ROW: bias indexed by output row (V^T gemm).
template<int CVTA, int CVTB, int BIAS_ROW, int OUT_F32>
__global__ __launch_bounds__(256) void gemm128(const void* __restrict__ Ap,
                                               const void* __restrict__ Bp,
                                               const float* __restrict__ bias,
                                               void* __restrict__ outp,
                                               int M, int N, int K,
                                               long sB, long sO) {
    __shared__ ushort At[128 * 32];
    __shared__ ushort Bt[128 * 32];
    int t = threadIdx.x;
    int wv = t >> 6, ln = t & 63, l = ln & 15, g = ln >> 4;
    int wrow = wv & 1, wcol = wv >> 1;
    int row0 = blockIdx.x * 128, col0 = blockIdx.y * 128;
    int srow = t >> 2, sko = (t & 3) * 8;  // 64 rows x 32k per 256-thread pass
    f32x4 acc[4][4];
#pragma unroll
    for (int i = 0; i < 4; i++)
#pragma unroll
        for (int j = 0; j < 4; j++) acc[i][j] = (f32x4){0, 0, 0, 0};

    for (int k0 = 0; k0 < K; k0 += 32) {
        __syncthreads();
        if (CVTA) {
            const float* a = (const float*)Ap;
#pragma unroll
            for (int c = 0; c < 2; c++) {
                const float* p = a + (size_t)(row0 + srow + 64 * c) * K + k0 + sko;
                float4 f0 = *(const float4*)p, f1 = *(const float4*)(p + 4);
                bf16x8 v;
                v[0] = (short)f2b(f0.x); v[1] = (short)f2b(f0.y);
                v[2] = (short)f2b(f0.z); v[3] = (short)f2b(f0.w);
                v[4] = (short)f2b(f1.x); v[5] = (short)f2b(f1.y);
                v[6] = (short)f2b(f1.z); v[7] = (short)f2b(f1.w);
                *(bf16x8*)(At + (srow + 64 * c) * 32 + sko) = v;
            }
        } else {
            const ushort* a = (const ushort*)Ap;
#pragma unroll
            for (int c = 0; c < 2; c++)
                gload16(a + (size_t)(row0 + srow + 64 * c) * K + k0 + sko,
                        At + (srow + 64 * c) * 32 + sko);
        }
        if (CVTB) {
            const float* b = (const float*)Bp + (size_t)blockIdx.z * sB;
#pragma unroll
            for (int c = 0; c < 2; c++) {
                const float* p = b + (size_t)(col0 + srow + 64 * c) * K + k0 + sko;
                float4 f0 = *(const float4*)p, f1 = *(const float4*)(p + 4);
                bf16x8 v;
                v[0] = (short)f2b(f0.x); v[1] = (short)f2b(f0.y);
                v[2] = (short)f2b(f0.z); v[3] = (short)f2b(f0.w);
                v[4] = (short)f2b(f1.x); v[5] = (short)f2b(f1.y);
                v[6] = (short)f2b(f1.z); v[7] = (short)f2b(f1.w);
                *(bf16x8*)(Bt + (srow + 64 * c) * 32 + sko) = v;
            }
        } else {
            const ushort* b = (const ushort*)Bp + (size_t)blockIdx.z * sB;
#pragma unroll
            for (int c = 0; c < 2; c++)
                gload16(b + (size_t)(col0 + srow + 64 * c) * K + k0 + sko,
                        Bt + (srow + 64 * c) * 32 + sko);
        }
        __syncthreads();
        bf16x8 ar[4], br[4];
#pragma unroll
        for (int i = 0; i < 4; i++)
            ar[i] = *(const bf16x8*)(At + (wrow * 64 + i * 16 + l) * 32 + g * 8);
#pragma unroll
        for (int j = 0; j < 4; j++)
            br[j] = *(const bf16x8*)(Bt + (wcol * 64 + j * 16 + l) * 32 + g * 8);
#pragma unroll
        for (int i = 0; i < 4; i++)
#pragma unroll
            for (int j = 0; j < 4; j++)
                acc[i][j] = __builtin_amdgcn_mfma_f32_16x16x32_bf16(ar[i], br[j], acc[i][j], 0, 0, 0);
    }
#pragma unroll
    for (int i = 0; i < 4; i++) {
#pragma unroll
        for (int j = 0; j < 4; j++) {
            int row = row0 + wrow * 64 + i * 16 + g * 4;
            int col = col0 + wcol * 64 + j * 16 + l;
#pragma unroll
            for (int r = 0; r < 4; r++) {
                float bv = BIAS_ROW ? bias[row + r] : bias[col];
                float o = acc[i][j][r] + bv;
                if (OUT_F32)
                    ((float*)outp + (size_t)blockIdx.z * sO)[(size_t)(row + r) * N + col] = o;
                else
                    ((ushort*)outp + (size_t)blockIdx.z * sO)[(size_t)(row + r) * N + col] = f2b(o);
            }
        }
    }
}

// One context: stream K (natural [m][d]) and V^T ([d][m]) tiles of TM=64.
// Wave owns 32 q rows (2 subtiles of 16); K/V frags register-reused across
// subtiles.  Max-free softmax: p = exp(s*scale), per-lane li partials.
__device__ __forceinline__ void attn_ctx(const ushort* __restrict__ Kp,
                                         const ushort* __restrict__ VTp,
                                         int M, int h,
                                         const bf16x8 (&aq)[2][2],
                                         ushort* __restrict__ Kl,
                                         ushort* __restrict__ Vl,
                                         ushort* __restrict__ Pw,
                                         f32x4 (&acc)[2][4], float (&li)[2][4],
                                         int t) {
    int ln = t & 63, l = ln & 15, g = ln >> 4;
    int sr = t >> 3, sc = (t & 7) * 8;
    const float sl2e = SCALE * 1.44269504088896f;  // fold into exp2
    for (int mt = 0; mt < M; mt += 64) {
        __syncthreads();
        const ushort* kg = Kp + (size_t)(mt + sr) * DIM + h * 64 + sc;
        bf16x8 k0 = *(const bf16x8*)kg;
        bf16x8 k1 = *(const bf16x8*)(kg + (size_t)32 * DIM);
        const ushort* vg = VTp + (size_t)(h * 64 + sr) * M + mt + sc;
        bf16x8 v0 = *(const bf16x8*)vg;
        bf16x8 v1 = *(const bf16x8*)(vg + (size_t)32 * M);
        *(bf16x8*)(Kl + sr * 72 + sc) = k0;
        *(bf16x8*)(Kl + (sr + 32) * 72 + sc) = k1;
        *(bf16x8*)(Vl + sr * 72 + sc) = v0;
        *(bf16x8*)(Vl + (sr + 32) * 72 + sc) = v1;
        __syncthreads();
#pragma unroll
        for (int tt = 0; tt < 4; tt++) {
            bf16x8 kb0 = *(const bf16x8*)(Kl + (16 * tt + l) * 72 + g * 8);
            bf16x8 kb1 = *(const bf16x8*)(Kl + (16 * tt + l) * 72 + 32 + g * 8);
            f32x4 s0 = {0, 0, 0, 0}, s1 = {0, 0, 0, 0};
            s0 = __builtin_amdgcn_mfma_f32_16x16x32_bf16(aq[0][0], kb0, s0, 0, 0, 0);
            s0 = __builtin_amdgcn_mfma_f32_16x16x32_bf16(aq[0][1], kb1, s0, 0, 0, 0);
            s1 = __builtin_amdgcn_mfma_f32_16x16x32_bf16(aq[1][0], kb0, s1, 0, 0, 0);
            s1 = __builtin_amdgcn_mfma_f32_16x16x32_bf16(aq[1][1], kb1, s1, 0, 0, 0);
#pragma unroll
            for (int r = 0; r < 4; r++) {
                float p0 = __expf(s0[r] * SCALE);
                float p1 = __expf(s1[r] * SCALE);
                li[0][r] += p0;
                li[1][r] += p1;
                Pw[(g * 4 + r) * 72 + 16 * tt + l] = f2b(p0);
                Pw[(16 + g * 4 + r) * 72 + 16 * tt + l] = f2b(p1);
            }
        }
        (void)sl2e;
        bf16x8 pa00 = *(const bf16x8*)(Pw + l * 72 + g * 8);
        bf16x8 pa01 = *(const bf16x8*)(Pw + l * 72 + 32 + g * 8);
        bf16x8 pa10 = *(const bf16x8*)(Pw + (16 + l) * 72 + g * 8);
        bf16x8 pa11 = *(const bf16x8*)(Pw + (16 + l) * 72 + 32 + g * 8);
#pragma unroll
        for (int c = 0; c < 4; c++) {
            bf16x8 vb0 = *(const bf16x8*)(Vl + (c * 16 + l) * 72 + g * 8);
            bf16x8 vb1 = *(const bf16x8*)(Vl + (c * 16 + l) * 72 + 32 + g * 8);
            acc[0][c] = __builtin_amdgcn_mfma_f32_16x16x32_bf16(pa00, vb0, acc[0][c], 0, 0, 0);
            acc[0][c] = __builtin_amdgcn_mfma_f32_16x16x32_bf16(pa01, vb1, acc[0][c], 0, 0, 0);
            acc[1][c] = __builtin_amdgcn_mfma_f32_16x16x32_bf16(pa10, vb0, acc[1][c], 0, 0, 0);
            acc[1][c] = __builtin_amdgcn_mfma_f32_16x16x32_bf16(pa11, vb1, acc[1][c], 0, 0, 0);
        }
    }
}

__global__ __launch_bounds__(256) void attn_kernel(const ushort* __restrict__ q,
                                                   const ushort* __restrict__ Ka,
                                                   const ushort* __restrict__ VTa,
                                                   const ushort* __restrict__ Ks,
                                                   const ushort* __restrict__ VTs,
                                                   ushort* __restrict__ y) {
    __shared__ ushort Kl[64 * 72];
    __shared__ ushort Vl[64 * 72];
    __shared__ ushort Pl[4 * 32 * 72];
    int t = threadIdx.x;
    int wv = t >> 6, ln = t & 63, l = ln & 15, g = ln >> 4;
    int h = blockIdx.y, bi = blockIdx.z;
    int q0 = blockIdx.x * 128 + wv * 32;
    bf16x8 aq[2][2];
#pragma unroll
    for (int s = 0; s < 2; s++)
#pragma unroll
        for (int kc = 0; kc < 2; kc++)
            aq[s][kc] = *(const bf16x8*)(q + (size_t)(bi * NQ + q0 + 16 * s + l) * DIM +
                                         h * 64 + kc * 32 + g * 8);
    ushort* Pw = Pl + wv * 32 * 72;

    f32x4 acc[2][4];
    float li[2][4];
#pragma unroll
    for (int s = 0; s < 2; s++) {
#pragma unroll
        for (int c = 0; c < 4; c++) acc[s][c] = (f32x4){0, 0, 0, 0};
#pragma unroll
        for (int r = 0; r < 4; r++) li[s][r] = 0.f;
    }
    // singer first (short), save normalized result in regs, then audio
    attn_ctx(Ks + (size_t)bi * MS * DIM, VTs + (size_t)bi * DIM * MS, MS, h,
             aq, Kl, Vl, Pw, acc, li, t);
    float yv[2][4][4];
#pragma unroll
    for (int s = 0; s < 2; s++)
#pragma unroll
        for (int r = 0; r < 4; r++) {
            float v = li[s][r];
            v += __shfl_xor(v, 1); v += __shfl_xor(v, 2);
            v += __shfl_xor(v, 4); v += __shfl_xor(v, 8);
            float inv = 1.f / v;
#pragma unroll
            for (int c = 0; c < 4; c++) yv[s][c][r] = acc[s][c][r] * inv;
        }
#pragma unroll
    for (int s = 0; s < 2; s++) {
#pragma unroll
        for (int c = 0; c < 4; c++) acc[s][c] = (f32x4){0, 0, 0, 0};
#pragma unroll
        for (int r = 0; r < 4; r++) li[s][r] = 0.f;
    }
    attn_ctx(Ka + (size_t)bi * MA * DIM, VTa + (size_t)bi * DIM * MA, MA, h,
             aq, Kl, Vl, Pw, acc, li, t);
#pragma unroll
    for (int s = 0; s < 2; s++)
#pragma unroll
        for (int r = 0; r < 4; r++) {
            float v = li[s][r];
            v += __shfl_xor(v, 1); v += __shfl_xor(v, 2);
            v += __shfl_xor(v, 4); v += __shfl_xor(v, 8);
            float inv = 1.f / v;
#pragma unroll
            for (int c = 0; c < 4; c++) {
                float o = yv[s][c][r] + acc[s][c][r] * inv;
                y[(size_t)(bi * NQ + q0 + 16 * s + g * 4 + r) * DIM +
                  h * 64 + c * 16 + l] = f2b(o);
            }
        }
}

extern "C" void kernel_launch(void* const* d_in, const int* in_sizes, int n_in,
                              void* d_out, int out_size, void* d_ws, size_t ws_size,
                              hipStream_t stream) {
    const float* x   = (const float*)d_in[0];
    const float* ac  = (const float*)d_in[1];
    const float* scx = (const float*)d_in[2];
    const float* Wq  = (const float*)d_in[3];
    const float* bq  = (const float*)d_in[4];
    const float* Wka = (const float*)d_in[5];
    const float* bka = (const float*)d_in[6];
    const float* Wva = (const float*)d_in[7];
    const float* bva = (const float*)d_in[8];
    const float* Wks = (const float*)d_in[9];
    const float* bks = (const float*)d_in[10];
    const float* Wvs = (const float*)d_in[11];
    const float* bvs = (const float*)d_in[12];
    const float* Wp  = (const float*)d_in[13];
    const float* bp  = (const float*)d_in[14];

    ushort* wb  = (ushort*)d_ws;          // 6 x 262144 bf16 weights
    ushort* wqb  = wb;
    ushort* wkab = wb + 262144;
    ushort* wvab = wb + 2 * 262144;
    ushort* wksb = wb + 3 * 262144;
    ushort* wvsb = wb + 4 * 262144;
    ushort* wpb  = wb + 5 * 262144;
    ushort* qb  = wb + 6 * 262144;        // [4*2048][512]
    ushort* kab = qb + 4194304;           // [4*2048][512]
    ushort* vta = kab + 4194304;          // [4][512][2048]  (V^T)
    ushort* ksb = vta + 4194304;          // [4*256][512]
    ushort* vts = ksb + 524288;           // [4][512][256]   (V^T)
    ushort* yb  = vts + 524288;           // [4*2048][512]
    // total ~37 MB

    cast_w6<<<dim3(256, 6), 256, 0, stream>>>(Wq, Wka, Wva, Wks, Wvs, Wp, wb);

    gemm128<1, 0, 0, 0><<<dim3(64, 4, 1), 256, 0, stream>>>(x,   wqb,  bq,  qb,  8192, 512, 512, 0, 0);
    gemm128<1, 0, 0, 0><<<dim3(64, 4, 1), 256, 0, stream>>>(ac,  wkab, bka, kab, 8192, 512, 512, 0, 0);
    gemm128<0, 1, 1, 0><<<dim3(4, 16, 4), 256, 0, stream>>>(wvab, ac, bva, vta, 512, 2048, 512,
                                                            2048L * 512, 512L * 2048);
    gemm128<1, 0, 0, 0><<<dim3(8, 4, 1),  256, 0, stream>>>(scx, wksb, bks, ksb, 1024, 512, 512, 0, 0);
    gemm128<0, 1, 1, 0><<<dim3(4, 2, 4),  256, 0, stream>>>(wvsb, scx, bvs, vts, 512, 256, 512,
                                                            256L * 512, 512L * 256);

    attn_kernel<<<dim3(16, 8, 4), 256, 0, stream>>>(qb, kab, vta, ksb, vts, yb);

    gemm128<0, 0, 0, 1><<<dim3(64, 4, 1), 256, 0, stream>>>(yb, wpb, bp, (float*)d_out,
                                                            8192, 512, 512, 0, 0);
}

// Round 3
// 259.642 us; speedup vs baseline: 2.0279x; 1.1530x over previous
//
#include <hip/hip_runtime.h>

// R2: pre-cast activations to bf16 (GEMMs become pure global_load_lds);
// 64x128 GEMM tiles (2 blocks/CU); attention gets register-preload pipeline,
// q prescaled by scale*log2e in GEMM epilogue (exp2f direct), 2-op bf16 round.
#define DIM 512
#define NQ 2048
#define MA 2048
#define MS 256
#define QSCALE 0.06375864651f  // 512^-0.5 * log2(e)

typedef __attribute__((ext_vector_type(8))) short bf16x8;
typedef __attribute__((ext_vector_type(4))) float f32x4;

__device__ __forceinline__ ushort f2b(float f) {
    uint u = __float_as_uint(f);
    u = (u + 0x7fffu + ((u >> 16) & 1u)) >> 16;
    return (ushort)u;
}

__device__ __forceinline__ void gload16(const ushort* g, ushort* l) {
    __builtin_amdgcn_global_load_lds(
        (const __attribute__((address_space(1))) void*)g,
        (__attribute__((address_space(3))) void*)l, 16, 0, 0);
}

__global__ __launch_bounds__(256) void cast_w6(const float* __restrict__ w0,
                                               const float* __restrict__ w1,
                                               const float* __restrict__ w2,
                                               const float* __restrict__ w3,
                                               const float* __restrict__ w4,
                                               const float* __restrict__ w5,
                                               ushort* __restrict__ out) {
    const float* ws[6] = {w0, w1, w2, w3, w4, w5};
    const float* src = ws[blockIdx.y];
    ushort* dst = out + (size_t)blockIdx.y * 262144;
    int i = blockIdx.x * 256 + threadIdx.x;
    float4 v = ((const float4*)src)[i];
    ushort4 o;
    o.x = f2b(v.x); o.y = f2b(v.y); o.z = f2b(v.z); o.w = f2b(v.w);
    ((ushort4*)dst)[i] = o;
}

// cast activations: y=0 -> x (1048576 f4), y=1 -> ac, y=2 -> scx (131072 f4)
__global__ __launch_bounds__(256) void cast_act(const float* __restrict__ x,
                                                const float* __restrict__ ac,
                                                const float* __restrict__ scx,
                                                ushort* __restrict__ xb,
                                                ushort* __restrict__ acb,
                                                ushort* __restrict__ scxb) {
    const float* srcs[3] = {x, ac, scx};
    ushort* dsts[3] = {xb, acb, scxb};
    int n4[3] = {1048576, 1048576, 131072};
    int y = blockIdx.y;
    int i = blockIdx.x * 256 + threadIdx.x;
    if (i >= n4[y]) return;
    float4 v = ((const float4*)srcs[y])[i];
    ushort4 o;
    o.x = f2b(v.x); o.y = f2b(v.y); o.z = f2b(v.z); o.w = f2b(v.w);
    ((ushort4*)dsts[y])[i] = o;
}

// C[64 x 128] tile: C = A[M x K] @ B[N x K]^T + bias. Both operands bf16,
// staged via global_load_lds(16B). 4 waves, wave wv owns cols wv*32.
template<int OUT_F32, int BIAS_ROW, int SCALEQ>
__global__ __launch_bounds__(256) void gemm64(const ushort* __restrict__ A,
                                              const ushort* __restrict__ B,
                                              const float* __restrict__ bias,
                                              void* __restrict__ outp,
                                              int M, int N, int K,
                                              long sB, long sO) {
    __shared__ ushort At[64 * 32];
    __shared__ ushort Bt[128 * 32];
    int t = threadIdx.x;
    int wv = t >> 6, ln = t & 63, l = ln & 15, g = ln >> 4;
    int row0 = blockIdx.x * 64, col0 = blockIdx.y * 128;
    int srow = t >> 2, sko = (t & 3) * 8;
    const ushort* Bz = B + (size_t)blockIdx.z * sB;
    f32x4 acc[4][2];
#pragma unroll
    for (int i = 0; i < 4; i++)
#pragma unroll
        for (int j = 0; j < 2; j++) acc[i][j] = (f32x4){0, 0, 0, 0};

    for (int k0 = 0; k0 < K; k0 += 32) {
        __syncthreads();
        gload16(A + (size_t)(row0 + srow) * K + k0 + sko, At + srow * 32 + sko);
#pragma unroll
        for (int c = 0; c < 2; c++)
            gload16(Bz + (size_t)(col0 + srow + 64 * c) * K + k0 + sko,
                    Bt + (srow + 64 * c) * 32 + sko);
        __syncthreads();
        bf16x8 ar[4], br[2];
#pragma unroll
        for (int i = 0; i < 4; i++)
            ar[i] = *(const bf16x8*)(At + (i * 16 + l) * 32 + g * 8);
#pragma unroll
        for (int j = 0; j < 2; j++)
            br[j] = *(const bf16x8*)(Bt + (wv * 32 + j * 16 + l) * 32 + g * 8);
#pragma unroll
        for (int i = 0; i < 4; i++)
#pragma unroll
            for (int j = 0; j < 2; j++)
                acc[i][j] = __builtin_amdgcn_mfma_f32_16x16x32_bf16(ar[i], br[j], acc[i][j], 0, 0, 0);
    }
#pragma unroll
    for (int i = 0; i < 4; i++) {
#pragma unroll
        for (int j = 0; j < 2; j++) {
            int row = row0 + i * 16 + g * 4;
            int col = col0 + wv * 32 + j * 16 + l;
#pragma unroll
            for (int r = 0; r < 4; r++) {
                float bv = BIAS_ROW ? bias[row + r] : bias[col];
                float o = acc[i][j][r] + bv;
                if (SCALEQ) o *= QSCALE;
                if (OUT_F32)
                    ((float*)outp + (size_t)blockIdx.z * sO)[(size_t)(row + r) * N + col] = o;
                else
                    ((ushort*)outp + (size_t)blockIdx.z * sO)[(size_t)(row + r) * N + col] = f2b(o);
            }
        }
    }
}

// Flash loop with register-preload pipeline.  Wave owns 32 q rows.
// q is prescaled by scale*log2e, so p = exp2(s) directly.
__device__ __forceinline__ void attn_ctx(const ushort* __restrict__ Kp,
                                         const ushort* __restrict__ VTp,
                                         int M, int h,
                                         const bf16x8 (&aq)[2][2],
                                         ushort* __restrict__ Kl,
                                         ushort* __restrict__ Vl,
                                         ushort* __restrict__ Pw,
                                         f32x4 (&acc)[2][4], float (&li)[2][4],
                                         int t) {
    int ln = t & 63, l = ln & 15, g = ln >> 4;
    int sr = t >> 3, sc = (t & 7) * 8;
    const ushort* kg = Kp + (size_t)sr * DIM + h * 64 + sc;
    const ushort* vg = VTp + (size_t)(h * 64 + sr) * M + sc;
    bf16x8 k0 = *(const bf16x8*)kg;
    bf16x8 k1 = *(const bf16x8*)(kg + (size_t)32 * DIM);
    bf16x8 v0 = *(const bf16x8*)vg;
    bf16x8 v1 = *(const bf16x8*)(vg + (size_t)32 * M);
    for (int mt = 0; mt < M; mt += 64) {
        __syncthreads();
        *(bf16x8*)(Kl + sr * 72 + sc) = k0;
        *(bf16x8*)(Kl + (sr + 32) * 72 + sc) = k1;
        *(bf16x8*)(Vl + sr * 72 + sc) = v0;
        *(bf16x8*)(Vl + (sr + 32) * 72 + sc) = v1;
        __syncthreads();
        if (mt + 64 < M) {  // preload next tile; latency hidden behind compute
            k0 = *(const bf16x8*)(kg + (size_t)(mt + 64) * DIM);
            k1 = *(const bf16x8*)(kg + (size_t)(mt + 96) * DIM);
            v0 = *(const bf16x8*)(vg + (mt + 64));
            v1 = *(const bf16x8*)(vg + (size_t)32 * M + (mt + 64));
        }
#pragma unroll
        for (int tt = 0; tt < 4; tt++) {
            bf16x8 kb0 = *(const bf16x8*)(Kl + (16 * tt + l) * 72 + g * 8);
            bf16x8 kb1 = *(const bf16x8*)(Kl + (16 * tt + l) * 72 + 32 + g * 8);
            f32x4 s0 = {0, 0, 0, 0}, s1 = {0, 0, 0, 0};
            s0 = __builtin_amdgcn_mfma_f32_16x16x32_bf16(aq[0][0], kb0, s0, 0, 0, 0);
            s0 = __builtin_amdgcn_mfma_f32_16x16x32_bf16(aq[0][1], kb1, s0, 0, 0, 0);
            s1 = __builtin_amdgcn_mfma_f32_16x16x32_bf16(aq[1][0], kb0, s1, 0, 0, 0);
            s1 = __builtin_amdgcn_mfma_f32_16x16x32_bf16(aq[1][1], kb1, s1, 0, 0, 0);
#pragma unroll
            for (int r = 0; r < 4; r++) {
                float p0 = exp2f(s0[r]);
                float p1 = exp2f(s1[r]);
                li[0][r] += p0;
                li[1][r] += p1;
                Pw[(g * 4 + r) * 72 + 16 * tt + l] =
                    (ushort)((__float_as_uint(p0) + 0x8000u) >> 16);
                Pw[(16 + g * 4 + r) * 72 + 16 * tt + l] =
                    (ushort)((__float_as_uint(p1) + 0x8000u) >> 16);
            }
        }
        bf16x8 pa00 = *(const bf16x8*)(Pw + l * 72 + g * 8);
        bf16x8 pa01 = *(const bf16x8*)(Pw + l * 72 + 32 + g * 8);
        bf16x8 pa10 = *(const bf16x8*)(Pw + (16 + l) * 72 + g * 8);
        bf16x8 pa11 = *(const bf16x8*)(Pw + (16 + l) * 72 + 32 + g * 8);
#pragma unroll
        for (int c = 0; c < 4; c++) {
            bf16x8 vb0 = *(const bf16x8*)(Vl + (c * 16 + l) * 72 + g * 8);
            bf16x8 vb1 = *(const bf16x8*)(Vl + (c * 16 + l) * 72 + 32 + g * 8);
            acc[0][c] = __builtin_amdgcn_mfma_f32_16x16x32_bf16(pa00, vb0, acc[0][c], 0, 0, 0);
            acc[0][c] = __builtin_amdgcn_mfma_f32_16x16x32_bf16(pa01, vb1, acc[0][c], 0, 0, 0);
            acc[1][c] = __builtin_amdgcn_mfma_f32_16x16x32_bf16(pa10, vb0, acc[1][c], 0, 0, 0);
            acc[1][c] = __builtin_amdgcn_mfma_f32_16x16x32_bf16(pa11, vb1, acc[1][c], 0, 0, 0);
        }
    }
}

__global__ __launch_bounds__(256) void attn_kernel(const ushort* __restrict__ q,
                                                   const ushort* __restrict__ Ka,
                                                   const ushort* __restrict__ VTa,
                                                   const ushort* __restrict__ Ks,
                                                   const ushort* __restrict__ VTs,
                                                   ushort* __restrict__ y) {
    __shared__ ushort Kl[64 * 72];
    __shared__ ushort Vl[64 * 72];
    __shared__ ushort Pl[4 * 32 * 72];
    int t = threadIdx.x;
    int wv = t >> 6, ln = t & 63, l = ln & 15, g = ln >> 4;
    int h = blockIdx.y, bi = blockIdx.z;
    int q0 = blockIdx.x * 128 + wv * 32;
    bf16x8 aq[2][2];
#pragma unroll
    for (int s = 0; s < 2; s++)
#pragma unroll
        for (int kc = 0; kc < 2; kc++)
            aq[s][kc] = *(const bf16x8*)(q + (size_t)(bi * NQ + q0 + 16 * s + l) * DIM +
                                         h * 64 + kc * 32 + g * 8);
    ushort* Pw = Pl + wv * 32 * 72;

    f32x4 acc[2][4];
    float li[2][4];
#pragma unroll
    for (int s = 0; s < 2; s++) {
#pragma unroll
        for (int c = 0; c < 4; c++) acc[s][c] = (f32x4){0, 0, 0, 0};
#pragma unroll
        for (int r = 0; r < 4; r++) li[s][r] = 0.f;
    }
    attn_ctx(Ks + (size_t)bi * MS * DIM, VTs + (size_t)bi * DIM * MS, MS, h,
             aq, Kl, Vl, Pw, acc, li, t);
    float yv[2][4][4];
#pragma unroll
    for (int s = 0; s < 2; s++)
#pragma unroll
        for (int r = 0; r < 4; r++) {
            float v = li[s][r];
            v += __shfl_xor(v, 1); v += __shfl_xor(v, 2);
            v += __shfl_xor(v, 4); v += __shfl_xor(v, 8);
            float inv = 1.f / v;
#pragma unroll
            for (int c = 0; c < 4; c++) yv[s][c][r] = acc[s][c][r] * inv;
        }
#pragma unroll
    for (int s = 0; s < 2; s++) {
#pragma unroll
        for (int c = 0; c < 4; c++) acc[s][c] = (f32x4){0, 0, 0, 0};
#pragma unroll
        for (int r = 0; r < 4; r++) li[s][r] = 0.f;
    }
    attn_ctx(Ka + (size_t)bi * MA * DIM, VTa + (size_t)bi * DIM * MA, MA, h,
             aq, Kl, Vl, Pw, acc, li, t);
#pragma unroll
    for (int s = 0; s < 2; s++)
#pragma unroll
        for (int r = 0; r < 4; r++) {
            float v = li[s][r];
            v += __shfl_xor(v, 1); v += __shfl_xor(v, 2);
            v += __shfl_xor(v, 4); v += __shfl_xor(v, 8);
            float inv = 1.f / v;
#pragma unroll
            for (int c = 0; c < 4; c++) {
                float o = yv[s][c][r] + acc[s][c][r] * inv;
                y[(size_t)(bi * NQ + q0 + 16 * s + g * 4 + r) * DIM +
                  h * 64 + c * 16 + l] = f2b(o);
            }
        }
}

extern "C" void kernel_launch(void* const* d_in, const int* in_sizes, int n_in,
                              void* d_out, int out_size, void* d_ws, size_t ws_size,
                              hipStream_t stream) {
    const float* x   = (const float*)d_in[0];
    const float* ac  = (const float*)d_in[1];
    const float* scx = (const float*)d_in[2];
    const float* Wq  = (const float*)d_in[3];
    const float* bq  = (const float*)d_in[4];
    const float* Wka = (const float*)d_in[5];
    const float* bka = (const float*)d_in[6];
    const float* Wva = (const float*)d_in[7];
    const float* bva = (const float*)d_in[8];
    const float* Wks = (const float*)d_in[9];
    const float* bks = (const float*)d_in[10];
    const float* Wvs = (const float*)d_in[11];
    const float* bvs = (const float*)d_in[12];
    const float* Wp  = (const float*)d_in[13];
    const float* bp  = (const float*)d_in[14];

    ushort* wb   = (ushort*)d_ws;         // 6 x 262144 bf16 weights
    ushort* wqb  = wb;
    ushort* wkab = wb + 262144;
    ushort* wvab = wb + 2 * 262144;
    ushort* wksb = wb + 3 * 262144;
    ushort* wvsb = wb + 4 * 262144;
    ushort* wpb  = wb + 5 * 262144;
    ushort* xb   = wb + 6 * 262144;       // [4*2048][512] bf16 (aliased as yb later)
    ushort* acb  = xb + 4194304;          // [4*2048][512]
    ushort* scxb = acb + 4194304;         // [4*256][512]
    ushort* qb   = scxb + 524288;         // [4*2048][512]
    ushort* kab  = qb + 4194304;          // [4*2048][512]
    ushort* vta  = kab + 4194304;         // [4][512][2048]  (V^T)
    ushort* ksb  = vta + 4194304;         // [4*256][512]
    ushort* vts  = ksb + 524288;          // [4][512][256]   (V^T)
    ushort* yb   = xb;                    // alias: x dead after q-GEMM
    // total ~48 MB

    cast_w6<<<dim3(256, 6), 256, 0, stream>>>(Wq, Wka, Wva, Wks, Wvs, Wp, wb);
    cast_act<<<dim3(4096, 3), 256, 0, stream>>>(x, ac, scx, xb, acb, scxb);

    // q (prescaled), k_audio, V^T_audio, k_singer, V^T_singer
    gemm64<0, 0, 1><<<dim3(128, 4, 1), 256, 0, stream>>>(xb,  wqb,  bq,  qb,  8192, 512, 512, 0, 0);
    gemm64<0, 0, 0><<<dim3(128, 4, 1), 256, 0, stream>>>(acb, wkab, bka, kab, 8192, 512, 512, 0, 0);
    gemm64<0, 1, 0><<<dim3(8, 16, 4),  256, 0, stream>>>(wvab, acb, bva, vta, 512, 2048, 512,
                                                         2048L * 512, 512L * 2048);
    gemm64<0, 0, 0><<<dim3(16, 4, 1),  256, 0, stream>>>(scxb, wksb, bks, ksb, 1024, 512, 512, 0, 0);
    gemm64<0, 1, 0><<<dim3(8, 2, 4),   256, 0, stream>>>(wvsb, scxb, bvs, vts, 512, 256, 512,
                                                         256L * 512, 512L * 256);

    attn_kernel<<<dim3(16, 8, 4), 256, 0, stream>>>(qb, kab, vta, ksb, vts, yb);

    gemm64<1, 0, 0><<<dim3(128, 4, 1), 256, 0, stream>>>(yb, wpb, bp, (float*)d_out,
                                                         8192, 512, 512, 0, 0);
}

// Round 4
// 246.100 us; speedup vs baseline: 2.1394x; 1.0550x over previous
//
#include <hip/hip_runtime.h>

// R3: S^T-trick attention (packed b64 P-writes, scalar li, 512-thr blocks,
// 16 waves/CU); all 5 pre-attn GEMMs fused into ONE launch via descriptor
// decode; casts fused; XOR k-chunk swizzle in GEMM LDS (gload16-compatible).
#define DIM 512
#define NQ 2048
#define MA 2048
#define MS 256
#define QSCALE 0.06375864651f  // 512^-0.5 * log2(e)

typedef __attribute__((ext_vector_type(8))) short bf16x8;
typedef __attribute__((ext_vector_type(4))) float f32x4;

__device__ __forceinline__ ushort f2b(float f) {
    uint u = __float_as_uint(f);
    u = (u + 0x7fffu + ((u >> 16) & 1u)) >> 16;
    return (ushort)u;
}

__device__ __forceinline__ void gload16(const ushort* g, ushort* l) {
    __builtin_amdgcn_global_load_lds(
        (const __attribute__((address_space(1))) void*)g,
        (__attribute__((address_space(3))) void*)l, 16, 0, 0);
}

// ---- fused cast: 6 weights + x + ac + scx -> contiguous bf16 region ----
__global__ __launch_bounds__(256) void cast_all(const float* __restrict__ w0,
                                                const float* __restrict__ w1,
                                                const float* __restrict__ w2,
                                                const float* __restrict__ w3,
                                                const float* __restrict__ w4,
                                                const float* __restrict__ w5,
                                                const float* __restrict__ x,
                                                const float* __restrict__ ac,
                                                const float* __restrict__ scx,
                                                ushort* __restrict__ dst) {
    int i = blockIdx.x * 256 + threadIdx.x;  // float4 index, 2621440 total
    const float* s;
    int o;
    if (i < 393216) {
        int w = i >> 16;
        s = w < 3 ? (w == 0 ? w0 : (w == 1 ? w1 : w2))
                  : (w == 3 ? w3 : (w == 4 ? w4 : w5));
        o = i & 65535;
    } else if (i < 1441792) { s = x;   o = i - 393216; }
    else if (i < 2490368)   { s = ac;  o = i - 1441792; }
    else                    { s = scx; o = i - 2490368; }
    float4 v = ((const float4*)s)[o];
    ushort4 u;
    u.x = f2b(v.x); u.y = f2b(v.y); u.z = f2b(v.z); u.w = f2b(v.w);
    ((ushort4*)dst)[i] = u;
}

// ---- fused GEMM: C = A @ B^T + bias, 128x128 tile, K=512, descriptor decode ----
struct GD {
    const ushort* A; const ushort* B; const float* bias; void* out;
    long sB, sO;
    int N, bx, by, blk0, biasrow, scaleq, outf32, pad;
};

__global__ __launch_bounds__(256) void gemm_fused(GD d0, GD d1, GD d2, GD d3, GD d4) {
    __shared__ ushort At[128 * 32];
    __shared__ ushort Bt[128 * 32];
    GD d = d0;
    int bid = blockIdx.x;
    if (bid >= d1.blk0) d = d1;
    if (bid >= d2.blk0) d = d2;
    if (bid >= d3.blk0) d = d3;
    if (bid >= d4.blk0) d = d4;
    int local = bid - d.blk0;
    int x = local % d.bx;
    int rem = local / d.bx;
    int y = rem % d.by;
    int z = rem / d.by;

    int t = threadIdx.x;
    int wv = t >> 6, ln = t & 63, l = ln & 15, g = ln >> 4;
    int wrow = wv & 1, wcol = wv >> 1;
    int row0 = x * 128, col0 = y * 128;
    int srow = t >> 2;
    int slot = (t & 3) * 8;
    int sko = ((t ^ srow) & 3) * 8;        // XOR-swizzled global k-chunk
    int kc8 = ((g ^ (l & 3)) & 3) * 8;     // reader un-swizzle
    const ushort* Ab = d.A;
    const ushort* Bb = d.B + (size_t)z * d.sB;
    int N = d.N;

    f32x4 acc[4][4];
#pragma unroll
    for (int i = 0; i < 4; i++)
#pragma unroll
        for (int j = 0; j < 4; j++) acc[i][j] = (f32x4){0, 0, 0, 0};

    for (int k0 = 0; k0 < 512; k0 += 32) {
        __syncthreads();
#pragma unroll
        for (int c = 0; c < 2; c++) {
            gload16(Ab + (size_t)(row0 + srow + 64 * c) * 512 + k0 + sko,
                    At + (srow + 64 * c) * 32 + slot);
            gload16(Bb + (size_t)(col0 + srow + 64 * c) * 512 + k0 + sko,
                    Bt + (srow + 64 * c) * 32 + slot);
        }
        __syncthreads();
        bf16x8 ar[4], br[4];
#pragma unroll
        for (int i = 0; i < 4; i++)
            ar[i] = *(const bf16x8*)(At + (wrow * 64 + i * 16 + l) * 32 + kc8);
#pragma unroll
        for (int j = 0; j < 4; j++)
            br[j] = *(const bf16x8*)(Bt + (wcol * 64 + j * 16 + l) * 32 + kc8);
#pragma unroll
        for (int i = 0; i < 4; i++)
#pragma unroll
            for (int j = 0; j < 4; j++)
                acc[i][j] = __builtin_amdgcn_mfma_f32_16x16x32_bf16(ar[i], br[j], acc[i][j], 0, 0, 0);
    }
#pragma unroll
    for (int i = 0; i < 4; i++) {
#pragma unroll
        for (int j = 0; j < 4; j++) {
            int row = row0 + wrow * 64 + i * 16 + g * 4;
            int col = col0 + wcol * 64 + j * 16 + l;
#pragma unroll
            for (int r = 0; r < 4; r++) {
                float bv = d.biasrow ? d.bias[row + r] : d.bias[col];
                float o = acc[i][j][r] + bv;
                if (d.scaleq) o *= QSCALE;
                if (d.outf32)
                    ((float*)d.out + (size_t)z * d.sO)[(size_t)(row + r) * N + col] = o;
                else
                    ((ushort*)d.out + (size_t)z * d.sO)[(size_t)(row + r) * N + col] = f2b(o);
            }
        }
    }
}

// ---- attention: S^T trick, wave owns 16 q rows, 8 waves/block ----
__device__ __forceinline__ void attn_ctx(const ushort* __restrict__ kg,
                                         const ushort* __restrict__ vg,
                                         int M, const bf16x8 (&aq)[2],
                                         ushort* __restrict__ Kl,
                                         ushort* __restrict__ Vl,
                                         ushort* __restrict__ Pw,
                                         f32x4 (&acc)[4], float& li,
                                         int l, int g, int sr, int sc) {
    bf16x8 k = *(const bf16x8*)kg;
    bf16x8 v = *(const bf16x8*)vg;
    for (int mt = 0; mt < M; mt += 64) {
        __syncthreads();
        *(bf16x8*)(Kl + sr * 72 + sc) = k;
        *(bf16x8*)(Vl + sr * 72 + sc) = v;
        __syncthreads();
        if (mt + 64 < M) {  // preload next tile behind compute
            k = *(const bf16x8*)(kg + (size_t)(mt + 64) * DIM);
            v = *(const bf16x8*)(vg + (mt + 64));
        }
#pragma unroll
        for (int tt = 0; tt < 4; tt++) {
            bf16x8 kb0 = *(const bf16x8*)(Kl + (16 * tt + l) * 72 + g * 8);
            bf16x8 kb1 = *(const bf16x8*)(Kl + (16 * tt + l) * 72 + 32 + g * 8);
            f32x4 s = {0, 0, 0, 0};
            // S^T[ctx][q]: A = K rows (ctx), B = Q rows (q)
            s = __builtin_amdgcn_mfma_f32_16x16x32_bf16(kb0, aq[0], s, 0, 0, 0);
            s = __builtin_amdgcn_mfma_f32_16x16x32_bf16(kb1, aq[1], s, 0, 0, 0);
            float p0 = exp2f(s[0]), p1 = exp2f(s[1]);
            float p2 = exp2f(s[2]), p3 = exp2f(s[3]);
            li += (p0 + p1) + (p2 + p3);
            uint u0 = (__float_as_uint(p0) + 0x8000u) >> 16;
            uint u1 = (__float_as_uint(p1) + 0x8000u) >> 16;
            uint u2 = (__float_as_uint(p2) + 0x8000u) >> 16;
            uint u3 = (__float_as_uint(p3) + 0x8000u) >> 16;
            uint2 pw;
            pw.x = u0 | (u1 << 16);
            pw.y = u2 | (u3 << 16);
            // P[q=l][ctx=16tt+4g .. +3]: 4 consecutive bf16 -> one b64 write
            *(uint2*)(Pw + l * 72 + 16 * tt + g * 4) = pw;
        }
        // PV: A = P[q][ctx] (natural A-layout b128), B = V^T[d][ctx]
        bf16x8 pa0 = *(const bf16x8*)(Pw + l * 72 + g * 8);
        bf16x8 pa1 = *(const bf16x8*)(Pw + l * 72 + 32 + g * 8);
#pragma unroll
        for (int c = 0; c < 4; c++) {
            bf16x8 vb0 = *(const bf16x8*)(Vl + (c * 16 + l) * 72 + g * 8);
            bf16x8 vb1 = *(const bf16x8*)(Vl + (c * 16 + l) * 72 + 32 + g * 8);
            acc[c] = __builtin_amdgcn_mfma_f32_16x16x32_bf16(pa0, vb0, acc[c], 0, 0, 0);
            acc[c] = __builtin_amdgcn_mfma_f32_16x16x32_bf16(pa1, vb1, acc[c], 0, 0, 0);
        }
    }
}

__global__ __launch_bounds__(512) void attn_kernel(const ushort* __restrict__ q,
                                                   const ushort* __restrict__ Ka,
                                                   const ushort* __restrict__ VTa,
                                                   const ushort* __restrict__ Ks,
                                                   const ushort* __restrict__ VTs,
                                                   ushort* __restrict__ y) {
    __shared__ ushort Kl[64 * 72];
    __shared__ ushort Vl[64 * 72];
    __shared__ ushort Pl[8 * 16 * 72];
    int t = threadIdx.x;
    int wv = t >> 6, ln = t & 63, l = ln & 15, g = ln >> 4;
    int h = blockIdx.y, bi = blockIdx.z;
    int q0 = blockIdx.x * 128 + wv * 16;
    bf16x8 aq[2];
    aq[0] = *(const bf16x8*)(q + (size_t)(bi * NQ + q0 + l) * DIM + h * 64 + g * 8);
    aq[1] = *(const bf16x8*)(q + (size_t)(bi * NQ + q0 + l) * DIM + h * 64 + 32 + g * 8);
    int sr = t >> 3, sc = (t & 7) * 8;
    ushort* Pw = Pl + wv * 16 * 72;

    f32x4 acc[4];
    float li = 0.f;
#pragma unroll
    for (int c = 0; c < 4; c++) acc[c] = (f32x4){0, 0, 0, 0};

    // singer (short) first
    {
        const ushort* kg = Ks + (size_t)bi * MS * DIM + (size_t)sr * DIM + h * 64 + sc;
        const ushort* vg = VTs + (size_t)bi * DIM * MS + (size_t)(h * 64 + sr) * MS + sc;
        attn_ctx(kg, vg, MS, aq, Kl, Vl, Pw, acc, li, l, g, sr, sc);
    }
    li += __shfl_xor(li, 16);
    li += __shfl_xor(li, 32);
    float yv[4][4];
    float inv[4];
#pragma unroll
    for (int r = 0; r < 4; r++) inv[r] = 1.f / __shfl(li, g * 4 + r);
#pragma unroll
    for (int c = 0; c < 4; c++)
#pragma unroll
        for (int r = 0; r < 4; r++) yv[c][r] = acc[c][r] * inv[r];

#pragma unroll
    for (int c = 0; c < 4; c++) acc[c] = (f32x4){0, 0, 0, 0};
    li = 0.f;
    {
        const ushort* kg = Ka + (size_t)bi * MA * DIM + (size_t)sr * DIM + h * 64 + sc;
        const ushort* vg = VTa + (size_t)bi * DIM * MA + (size_t)(h * 64 + sr) * MA + sc;
        attn_ctx(kg, vg, MA, aq, Kl, Vl, Pw, acc, li, l, g, sr, sc);
    }
    li += __shfl_xor(li, 16);
    li += __shfl_xor(li, 32);
#pragma unroll
    for (int r = 0; r < 4; r++) inv[r] = 1.f / __shfl(li, g * 4 + r);
#pragma unroll
    for (int c = 0; c < 4; c++)
#pragma unroll
        for (int r = 0; r < 4; r++) {
            float o = yv[c][r] + acc[c][r] * inv[r];
            y[(size_t)(bi * NQ + q0 + g * 4 + r) * DIM + h * 64 + c * 16 + l] = f2b(o);
        }
}

extern "C" void kernel_launch(void* const* d_in, const int* in_sizes, int n_in,
                              void* d_out, int out_size, void* d_ws, size_t ws_size,
                              hipStream_t stream) {
    const float* x   = (const float*)d_in[0];
    const float* ac  = (const float*)d_in[1];
    const float* scx = (const float*)d_in[2];
    const float* Wq  = (const float*)d_in[3];
    const float* bq  = (const float*)d_in[4];
    const float* Wka = (const float*)d_in[5];
    const float* bka = (const float*)d_in[6];
    const float* Wva = (const float*)d_in[7];
    const float* bva = (const float*)d_in[8];
    const float* Wks = (const float*)d_in[9];
    const float* bks = (const float*)d_in[10];
    const float* Wvs = (const float*)d_in[11];
    const float* bvs = (const float*)d_in[12];
    const float* Wp  = (const float*)d_in[13];
    const float* bp  = (const float*)d_in[14];

    ushort* wb   = (ushort*)d_ws;         // cast dst region is contiguous:
    ushort* wqb  = wb;                    // [6 weights][xb][acb][scxb]
    ushort* wkab = wb + 262144;
    ushort* wvab = wb + 2 * 262144;
    ushort* wksb = wb + 3 * 262144;
    ushort* wvsb = wb + 4 * 262144;
    ushort* wpb  = wb + 5 * 262144;
    ushort* xb   = wb + 6 * 262144;       // [8192][512]
    ushort* acb  = xb + 4194304;          // [8192][512]
    ushort* scxb = acb + 4194304;         // [1024][512]
    ushort* qb   = scxb + 524288;         // [8192][512] prescaled q
    ushort* kab  = qb + 4194304;          // [8192][512]
    ushort* vta  = kab + 4194304;         // [4][512][2048] V^T
    ushort* ksb  = vta + 4194304;         // [1024][512]
    ushort* vts  = ksb + 524288;          // [4][512][256]  V^T
    ushort* yb   = xb;                    // alias: x dead after gemm_fused

    cast_all<<<10240, 256, 0, stream>>>(Wq, Wka, Wva, Wks, Wvs, Wp, x, ac, scx, wb);

    GD gq   = {xb,   wqb,  bq,  qb,  0, 0,               512,  64, 4,  0,   0, 1, 0, 0};
    GD gka  = {acb,  wkab, bka, kab, 0, 0,               512,  64, 4,  256, 0, 0, 0, 0};
    GD gvta = {wvab, acb,  bva, vta, 2048L * 512, 512L * 2048, 2048, 4, 16, 512, 1, 0, 0, 0};
    GD gks  = {scxb, wksb, bks, ksb, 0, 0,               512,  8,  4,  768, 0, 0, 0, 0};
    GD gvts = {wvsb, scxb, bvs, vts, 256L * 512, 512L * 256,   256,  4,  2,  800, 1, 0, 0, 0};
    gemm_fused<<<832, 256, 0, stream>>>(gq, gka, gvta, gks, gvts);

    attn_kernel<<<dim3(16, 8, 4), 512, 0, stream>>>(qb, kab, vta, ksb, vts, yb);

    GD gpr = {yb, wpb, bp, d_out, 0, 0, 512, 64, 4, 0, 0, 0, 1, 0};
    GD gnv = {nullptr, nullptr, nullptr, nullptr, 0, 0, 0, 1, 1, 1 << 30, 0, 0, 0, 0};
    gemm_fused<<<256, 256, 0, stream>>>(gpr, gnv, gnv, gnv, gnv);
}